// Round 1
// baseline (1453.454 us; speedup 1.0000x reference)
//
#include <hip/hip_runtime.h>
#include <math.h>

#define N_NODES 100000
#define N_EDGES 1600000
#define HID 64
#define N_LAYERS 3
#define N_GRAPHS 500

__device__ __forceinline__ float elu_f(float x) { return x > 0.f ? x : expm1f(x); }

__global__ void k_deg_init(float* deg, int n) {
    int i = blockIdx.x * blockDim.x + threadIdx.x;
    if (i < n) deg[i] = 1.0f;   // self-loop contributes 1
}

__global__ void k_deg_count(const int* __restrict__ ei, float* deg, int E) {
    int e = blockIdx.x * blockDim.x + threadIdx.x;
    if (e < E) atomicAdd(&deg[ei[E + e]], 1.0f);   // dst = ei[E + e]
}

__global__ void k_rsqrt(float* deg, int n) {
    int i = blockIdx.x * blockDim.x + threadIdx.x;
    if (i < n) deg[i] = rsqrtf(deg[i]);
}

// One wave per row. Computes B = act(X) @ W and A = B * dis^2 (self-loop init).
// act(X) = elu(X + bias_prev) when act != 0, else X.
__global__ void k_gemm(const float* __restrict__ X, const float* __restrict__ W,
                       const float* __restrict__ bias, int act,
                       const float* __restrict__ dis,
                       float* __restrict__ B, float* __restrict__ A, int n) {
    int lane = threadIdx.x & 63;
    int wid = (blockIdx.x * blockDim.x + threadIdx.x) >> 6;
    if (wid >= n) return;
    float xv = X[(size_t)wid * HID + lane];
    if (act) xv = elu_f(xv + bias[lane]);
    float acc = 0.f;
#pragma unroll
    for (int k = 0; k < HID; k++)
        acc = fmaf(__shfl(xv, k), W[k * HID + lane], acc);
    B[(size_t)wid * HID + lane] = acc;
    float d = dis[wid];
    A[(size_t)wid * HID + lane] = acc * d * d;
}

// One wave per edge: A[dst] += B[src] * dis[src]*dis[dst]
__global__ void k_scatter(const int* __restrict__ ei, const float* __restrict__ dis,
                          const float* __restrict__ B, float* __restrict__ A, int E) {
    int lane = threadIdx.x & 63;
    int wid = (blockIdx.x * blockDim.x + threadIdx.x) >> 6;
    if (wid >= E) return;
    int s = ei[wid];
    int d = ei[E + wid];
    float nr = dis[s] * dis[d];
    float v = B[(size_t)s * HID + lane] * nr;
    atomicAdd(&A[(size_t)d * HID + lane], v);
}

// One wave per node: masked segment-sum into per-graph accumulators.
// Applies the final layer's bias+ELU on load.
__global__ void k_pool(const float* __restrict__ A, const float* __restrict__ bias,
                       const int* __restrict__ mask, const int* __restrict__ batch,
                       float* __restrict__ num, float* __restrict__ den, int n) {
    int lane = threadIdx.x & 63;
    int wid = (blockIdx.x * blockDim.x + threadIdx.x) >> 6;
    if (wid >= n) return;
    if (!mask[wid]) return;
    int g = batch[wid];
    float h = elu_f(A[(size_t)wid * HID + lane] + bias[lane]);
    atomicAdd(&num[g * HID + lane], h);
    if (lane == 0) atomicAdd(&den[g], 1.0f);
}

// One wave per graph: out[g] = dot(num[g]/max(den[g],1), w) + b
__global__ void k_final(const float* __restrict__ num, const float* __restrict__ den,
                        const float* __restrict__ w, const float* __restrict__ b,
                        float* __restrict__ out, int G) {
    int lane = threadIdx.x & 63;
    int g = (blockIdx.x * blockDim.x + threadIdx.x) >> 6;
    if (g >= G) return;
    float v = num[g * HID + lane] / fmaxf(den[g], 1.0f) * w[lane];
#pragma unroll
    for (int off = 32; off > 0; off >>= 1) v += __shfl_down(v, off);
    if (lane == 0) out[g] = v + b[0];
}

extern "C" void kernel_launch(void* const* d_in, const int* in_sizes, int n_in,
                              void* d_out, int out_size, void* d_ws, size_t ws_size,
                              hipStream_t stream) {
    const float* x     = (const float*)d_in[0];
    const int*   ei    = (const int*)d_in[1];   // [2, E] flat: src = ei[e], dst = ei[E+e]
    const int*   mask  = (const int*)d_in[2];
    const int*   batch = (const int*)d_in[3];
    const float* Ws    = (const float*)d_in[4]; // [3, 64, 64]
    const float* bs    = (const float*)d_in[5]; // [3, 64]
    const float* lw    = (const float*)d_in[6]; // [64]
    const float* lb    = (const float*)d_in[7]; // [1]
    float* out = (float*)d_out;

    float* ws  = (float*)d_ws;
    float* A   = ws;                             // N*64 (scatter accumulator / h)
    float* B   = A + (size_t)N_NODES * HID;      // N*64 (h @ W)
    float* dis = B + (size_t)N_NODES * HID;      // N
    float* num = dis + N_NODES;                  // G*64
    float* den = num + (size_t)N_GRAPHS * HID;   // G

    // zero pooling accumulators (num and den are contiguous)
    hipMemsetAsync(num, 0, ((size_t)N_GRAPHS * HID + N_GRAPHS) * sizeof(float), stream);

    // degree -> rsqrt (self loops included)
    k_deg_init<<<(N_NODES + 255) / 256, 256, 0, stream>>>(dis, N_NODES);
    k_deg_count<<<(N_EDGES + 255) / 256, 256, 0, stream>>>(ei, dis, N_EDGES);
    k_rsqrt<<<(N_NODES + 255) / 256, 256, 0, stream>>>(dis, N_NODES);

    const int gemm_blocks    = (N_NODES + 3) / 4;  // 4 waves/block, 1 row/wave
    const int scatter_blocks = (N_EDGES + 3) / 4;  // 1 edge/wave

    for (int l = 0; l < N_LAYERS; l++) {
        const float* in      = (l == 0) ? x : A;
        const float* bias_in = (l == 0) ? bs : bs + (l - 1) * HID;
        k_gemm<<<gemm_blocks, 256, 0, stream>>>(in, Ws + (size_t)l * HID * HID,
                                                bias_in, (l == 0) ? 0 : 1,
                                                dis, B, A, N_NODES);
        k_scatter<<<scatter_blocks, 256, 0, stream>>>(ei, dis, B, A, N_EDGES);
    }

    k_pool<<<(N_NODES + 3) / 4, 256, 0, stream>>>(A, bs + 2 * HID, mask, batch,
                                                  num, den, N_NODES);
    k_final<<<(N_GRAPHS + 3) / 4, 256, 0, stream>>>(num, den, lw, lb, out, N_GRAPHS);
}

// Round 2
// 950.775 us; speedup vs baseline: 1.5287x; 1.5287x over previous
//
#include <hip/hip_runtime.h>
#include <math.h>

#define N_NODES 100000
#define N_EDGES 1600000
#define HID 64
#define N_LAYERS 3
#define N_GRAPHS 500
#define NB_SCAN ((N_NODES + 255) / 256)   // 391

__device__ __forceinline__ float elu_f(float x) { return x > 0.f ? x : expm1f(x); }

// ---- CSR build (once per launch) ----

__global__ void k_count(const int* __restrict__ ei, int* __restrict__ cnt, int E) {
    int e = blockIdx.x * blockDim.x + threadIdx.x;
    if (e < E) atomicAdd(&cnt[ei[E + e]], 1);   // dst = ei[E + e]
}

// per-block partial sums of counts
__global__ void k_scan1(const int* __restrict__ cnt, int* __restrict__ bsum, int n) {
    __shared__ int s[256];
    int t = threadIdx.x;
    int i = blockIdx.x * 256 + t;
    s[t] = (i < n) ? cnt[i] : 0;
    __syncthreads();
    for (int o = 128; o > 0; o >>= 1) {
        if (t < o) s[t] += s[t + o];
        __syncthreads();
    }
    if (t == 0) bsum[blockIdx.x] = s[0];
}

// single-block exclusive scan of block sums (NB_SCAN <= 512)
__global__ void k_scan2(const int* __restrict__ bsum, int* __restrict__ bpre, int nb) {
    __shared__ int s[512];
    int t = threadIdx.x;
    int v = (t < nb) ? bsum[t] : 0;
    s[t] = v;
    __syncthreads();
    for (int o = 1; o < 512; o <<= 1) {
        int u = (t >= o) ? s[t - o] : 0;
        __syncthreads();
        s[t] += u;
        __syncthreads();
    }
    if (t < nb) bpre[t] = s[t] - v;
}

// per-block exclusive scan + block prefix -> offsets, cursor, dis
__global__ void k_scan3(const int* __restrict__ cnt, const int* __restrict__ bpre,
                        int* __restrict__ off, int* __restrict__ cur,
                        float* __restrict__ dis, int n) {
    __shared__ int s[256];
    int t = threadIdx.x;
    int i = blockIdx.x * 256 + t;
    int c = (i < n) ? cnt[i] : 0;
    s[t] = c;
    __syncthreads();
    for (int o = 1; o < 256; o <<= 1) {
        int u = (t >= o) ? s[t - o] : 0;
        __syncthreads();
        s[t] += u;
        __syncthreads();
    }
    int excl = s[t] - c + bpre[blockIdx.x];
    if (i < n) {
        off[i] = excl;
        cur[i] = excl;
        dis[i] = rsqrtf((float)c + 1.0f);   // +1 self loop
    }
    if (i == n - 1) off[n] = excl + c;
}

// place each edge into its dst segment; precompute norm
__global__ void k_fill(const int* __restrict__ ei, const float* __restrict__ dis,
                       int* __restrict__ cur, int* __restrict__ psrc,
                       float* __restrict__ pnorm, int E) {
    int e = blockIdx.x * blockDim.x + threadIdx.x;
    if (e >= E) return;
    int s = ei[e];
    int d = ei[E + e];
    int pos = atomicAdd(&cur[d], 1);
    psrc[pos] = s;
    pnorm[pos] = dis[s] * dis[d];
}

// ---- per-layer kernels ----

// One wave per row. B = act(X) @ W, act = elu(x + prev_bias) for layers > 0.
__global__ void k_gemm(const float* __restrict__ X, const float* __restrict__ W,
                       const float* __restrict__ bias, int act,
                       float* __restrict__ B, int n) {
    int lane = threadIdx.x & 63;
    int wid = (blockIdx.x * blockDim.x + threadIdx.x) >> 6;
    if (wid >= n) return;
    float xv = X[(size_t)wid * HID + lane];
    if (act) xv = elu_f(xv + bias[lane]);
    float acc = 0.f;
#pragma unroll
    for (int k = 0; k < HID; k++)
        acc = fmaf(__shfl(xv, k), W[k * HID + lane], acc);
    B[(size_t)wid * HID + lane] = acc;
}

// One wave per dst node: A[dst] = B[dst]*dis^2 + sum_{in-edges} B[src]*norm
__global__ void k_agg(const int* __restrict__ off, const int* __restrict__ psrc,
                      const float* __restrict__ pnorm, const float* __restrict__ dis,
                      const float* __restrict__ B, float* __restrict__ A, int n) {
    int lane = threadIdx.x & 63;
    int node = (blockIdx.x * blockDim.x + threadIdx.x) >> 6;
    if (node >= n) return;
    float d = dis[node];
    float acc = B[(size_t)node * HID + lane] * d * d;
    int p0 = off[node], p1 = off[node + 1];
    for (int p = p0; p < p1; ++p) {
        int s = psrc[p];
        float nr = pnorm[p];
        acc = fmaf(B[(size_t)s * HID + lane], nr, acc);
    }
    A[(size_t)node * HID + lane] = acc;
}

// One wave per node: masked segment-sum into per-graph accumulators (bias+ELU on load).
__global__ void k_pool(const float* __restrict__ A, const float* __restrict__ bias,
                       const int* __restrict__ mask, const int* __restrict__ batch,
                       float* __restrict__ num, float* __restrict__ den, int n) {
    int lane = threadIdx.x & 63;
    int wid = (blockIdx.x * blockDim.x + threadIdx.x) >> 6;
    if (wid >= n) return;
    if (!mask[wid]) return;
    int g = batch[wid];
    float h = elu_f(A[(size_t)wid * HID + lane] + bias[lane]);
    atomicAdd(&num[g * HID + lane], h);
    if (lane == 0) atomicAdd(&den[g], 1.0f);
}

// One wave per graph: out[g] = dot(num[g]/max(den[g],1), w) + b
__global__ void k_final(const float* __restrict__ num, const float* __restrict__ den,
                        const float* __restrict__ w, const float* __restrict__ b,
                        float* __restrict__ out, int G) {
    int lane = threadIdx.x & 63;
    int g = (blockIdx.x * blockDim.x + threadIdx.x) >> 6;
    if (g >= G) return;
    float v = num[g * HID + lane] / fmaxf(den[g], 1.0f) * w[lane];
#pragma unroll
    for (int off = 32; off > 0; off >>= 1) v += __shfl_down(v, off);
    if (lane == 0) out[g] = v + b[0];
}

extern "C" void kernel_launch(void* const* d_in, const int* in_sizes, int n_in,
                              void* d_out, int out_size, void* d_ws, size_t ws_size,
                              hipStream_t stream) {
    const float* x     = (const float*)d_in[0];
    const int*   ei    = (const int*)d_in[1];   // [2, E]: src = ei[e], dst = ei[E+e]
    const int*   mask  = (const int*)d_in[2];
    const int*   batch = (const int*)d_in[3];
    const float* Ws    = (const float*)d_in[4]; // [3, 64, 64]
    const float* bs    = (const float*)d_in[5]; // [3, 64]
    const float* lw    = (const float*)d_in[6]; // [64]
    const float* lb    = (const float*)d_in[7]; // [1]
    float* out = (float*)d_out;

    // workspace layout (all 4-byte elements)
    float* ws    = (float*)d_ws;
    float* A     = ws;                               // N*64
    float* B     = A + (size_t)N_NODES * HID;        // N*64
    float* dis   = B + (size_t)N_NODES * HID;        // N
    float* pnorm = dis + N_NODES;                    // E
    float* num   = pnorm + N_EDGES;                  // G*64
    float* den   = num + (size_t)N_GRAPHS * HID;     // G
    int*   cnt   = (int*)(den + N_GRAPHS);           // N
    int*   off   = cnt + N_NODES;                    // N+1
    int*   cur   = off + N_NODES + 1;                // N
    int*   bsum  = cur + N_NODES;                    // NB_SCAN
    int*   bpre  = bsum + NB_SCAN;                   // NB_SCAN
    int*   psrc  = bpre + NB_SCAN;                   // E

    hipMemsetAsync(num, 0, ((size_t)N_GRAPHS * HID + N_GRAPHS) * sizeof(float), stream);
    hipMemsetAsync(cnt, 0, (size_t)N_NODES * sizeof(int), stream);

    // ---- CSR build ----
    k_count<<<(N_EDGES + 255) / 256, 256, 0, stream>>>(ei, cnt, N_EDGES);
    k_scan1<<<NB_SCAN, 256, 0, stream>>>(cnt, bsum, N_NODES);
    k_scan2<<<1, 512, 0, stream>>>(bsum, bpre, NB_SCAN);
    k_scan3<<<NB_SCAN, 256, 0, stream>>>(cnt, bpre, off, cur, dis, N_NODES);
    k_fill<<<(N_EDGES + 255) / 256, 256, 0, stream>>>(ei, dis, cur, psrc, pnorm, N_EDGES);

    // ---- layers ----
    const int row_blocks = (N_NODES + 3) / 4;   // 4 waves/block, 1 row/wave
    for (int l = 0; l < N_LAYERS; l++) {
        const float* in      = (l == 0) ? x : A;
        const float* bias_in = (l == 0) ? bs : bs + (l - 1) * HID;
        k_gemm<<<row_blocks, 256, 0, stream>>>(in, Ws + (size_t)l * HID * HID,
                                               bias_in, (l == 0) ? 0 : 1, B, N_NODES);
        k_agg<<<row_blocks, 256, 0, stream>>>(off, psrc, pnorm, dis, B, A, N_NODES);
    }

    k_pool<<<(N_NODES + 3) / 4, 256, 0, stream>>>(A, bs + 2 * HID, mask, batch,
                                                  num, den, N_NODES);
    k_final<<<(N_GRAPHS + 3) / 4, 256, 0, stream>>>(num, den, lw, lb, out, N_GRAPHS);
}

// Round 3
// 689.826 us; speedup vs baseline: 2.1070x; 1.3783x over previous
//
#include <hip/hip_runtime.h>
#include <math.h>

#define N_NODES 100000
#define N_EDGES 1600000
#define HID 64
#define N_LAYERS 3
#define N_GRAPHS 500
#define NB_SCAN ((N_NODES + 255) / 256)   // 391

__device__ __forceinline__ float elu_f(float x) { return x > 0.f ? x : expm1f(x); }

// ---- CSR build (once per launch) ----

__global__ void k_count(const int* __restrict__ ei, int* __restrict__ cnt, int E) {
    int e = blockIdx.x * blockDim.x + threadIdx.x;
    if (e < E) atomicAdd(&cnt[ei[E + e]], 1);   // dst = ei[E + e]
}

__global__ void k_scan1(const int* __restrict__ cnt, int* __restrict__ bsum, int n) {
    __shared__ int s[256];
    int t = threadIdx.x;
    int i = blockIdx.x * 256 + t;
    s[t] = (i < n) ? cnt[i] : 0;
    __syncthreads();
    for (int o = 128; o > 0; o >>= 1) {
        if (t < o) s[t] += s[t + o];
        __syncthreads();
    }
    if (t == 0) bsum[blockIdx.x] = s[0];
}

__global__ void k_scan2(const int* __restrict__ bsum, int* __restrict__ bpre, int nb) {
    __shared__ int s[512];
    int t = threadIdx.x;
    int v = (t < nb) ? bsum[t] : 0;
    s[t] = v;
    __syncthreads();
    for (int o = 1; o < 512; o <<= 1) {
        int u = (t >= o) ? s[t - o] : 0;
        __syncthreads();
        s[t] += u;
        __syncthreads();
    }
    if (t < nb) bpre[t] = s[t] - v;
}

__global__ void k_scan3(const int* __restrict__ cnt, const int* __restrict__ bpre,
                        int* __restrict__ off, int* __restrict__ cur,
                        float* __restrict__ dis, int n) {
    __shared__ int s[256];
    int t = threadIdx.x;
    int i = blockIdx.x * 256 + t;
    int c = (i < n) ? cnt[i] : 0;
    s[t] = c;
    __syncthreads();
    for (int o = 1; o < 256; o <<= 1) {
        int u = (t >= o) ? s[t - o] : 0;
        __syncthreads();
        s[t] += u;
        __syncthreads();
    }
    int excl = s[t] - c + bpre[blockIdx.x];
    if (i < n) {
        off[i] = excl;
        cur[i] = excl;
        dis[i] = rsqrtf((float)c + 1.0f);   // +1 self loop
    }
    if (i == n - 1) off[n] = excl + c;
}

__global__ void k_fill(const int* __restrict__ ei, int* __restrict__ cur,
                       int* __restrict__ psrc, int E) {
    int e = blockIdx.x * blockDim.x + threadIdx.x;
    if (e >= E) return;
    int s = ei[e];
    int d = ei[E + e];
    int pos = atomicAdd(&cur[d], 1);
    psrc[pos] = s;
}

// ---- per-layer kernels ----

// One wave per row. B = (act(X) @ W) * dis[row]   (dis folded in so the edge
// aggregation needs no per-edge norm: A[d] = dis[d]*(sum B[src] + B[d]))
__global__ void k_gemm(const float* __restrict__ X, const float* __restrict__ W,
                       const float* __restrict__ bias, int act,
                       const float* __restrict__ dis, float* __restrict__ B, int n) {
    int lane = threadIdx.x & 63;
    int wid = (blockIdx.x * blockDim.x + threadIdx.x) >> 6;
    if (wid >= n) return;
    float xv = X[(size_t)wid * HID + lane];
    if (act) xv = elu_f(xv + bias[lane]);
    float acc = 0.f;
#pragma unroll
    for (int k = 0; k < HID; k++)
        acc = fmaf(__shfl(xv, k), W[k * HID + lane], acc);
    B[(size_t)wid * HID + lane] = acc * dis[wid];
}

// One wave per dst node: A[dst] = dis[dst] * (B[dst] + sum_{in} B[src])
// 8-wide unrolled gather to keep 8 independent vmem loads in flight.
__global__ void k_agg(const int* __restrict__ off, const int* __restrict__ psrc,
                      const float* __restrict__ dis, const float* __restrict__ B,
                      float* __restrict__ A, int n) {
    int lane = threadIdx.x & 63;
    int node = __builtin_amdgcn_readfirstlane((blockIdx.x * blockDim.x + threadIdx.x) >> 6);
    if (node >= n) return;
    float acc = B[(size_t)node * HID + lane];
    int p0 = off[node], p1 = off[node + 1];
    int p = p0;
    for (; p + 8 <= p1; p += 8) {
        int s0 = psrc[p+0], s1 = psrc[p+1], s2 = psrc[p+2], s3 = psrc[p+3];
        int s4 = psrc[p+4], s5 = psrc[p+5], s6 = psrc[p+6], s7 = psrc[p+7];
        float b0 = B[(size_t)s0*HID+lane], b1 = B[(size_t)s1*HID+lane];
        float b2 = B[(size_t)s2*HID+lane], b3 = B[(size_t)s3*HID+lane];
        float b4 = B[(size_t)s4*HID+lane], b5 = B[(size_t)s5*HID+lane];
        float b6 = B[(size_t)s6*HID+lane], b7 = B[(size_t)s7*HID+lane];
        acc += ((b0 + b1) + (b2 + b3)) + ((b4 + b5) + (b6 + b7));
    }
    if (p + 4 <= p1) {
        int s0 = psrc[p+0], s1 = psrc[p+1], s2 = psrc[p+2], s3 = psrc[p+3];
        float b0 = B[(size_t)s0*HID+lane], b1 = B[(size_t)s1*HID+lane];
        float b2 = B[(size_t)s2*HID+lane], b3 = B[(size_t)s3*HID+lane];
        acc += (b0 + b1) + (b2 + b3);
        p += 4;
    }
    if (p + 2 <= p1) {
        int s0 = psrc[p+0], s1 = psrc[p+1];
        float b0 = B[(size_t)s0*HID+lane], b1 = B[(size_t)s1*HID+lane];
        acc += b0 + b1;
        p += 2;
    }
    if (p < p1) acc += B[(size_t)psrc[p]*HID+lane];
    A[(size_t)node * HID + lane] = acc * dis[node];
}

__global__ void k_pool(const float* __restrict__ A, const float* __restrict__ bias,
                       const int* __restrict__ mask, const int* __restrict__ batch,
                       float* __restrict__ num, float* __restrict__ den, int n) {
    int lane = threadIdx.x & 63;
    int wid = (blockIdx.x * blockDim.x + threadIdx.x) >> 6;
    if (wid >= n) return;
    if (!mask[wid]) return;
    int g = batch[wid];
    float h = elu_f(A[(size_t)wid * HID + lane] + bias[lane]);
    atomicAdd(&num[g * HID + lane], h);
    if (lane == 0) atomicAdd(&den[g], 1.0f);
}

__global__ void k_final(const float* __restrict__ num, const float* __restrict__ den,
                        const float* __restrict__ w, const float* __restrict__ b,
                        float* __restrict__ out, int G) {
    int lane = threadIdx.x & 63;
    int g = (blockIdx.x * blockDim.x + threadIdx.x) >> 6;
    if (g >= G) return;
    float v = num[g * HID + lane] / fmaxf(den[g], 1.0f) * w[lane];
#pragma unroll
    for (int off = 32; off > 0; off >>= 1) v += __shfl_down(v, off);
    if (lane == 0) out[g] = v + b[0];
}

extern "C" void kernel_launch(void* const* d_in, const int* in_sizes, int n_in,
                              void* d_out, int out_size, void* d_ws, size_t ws_size,
                              hipStream_t stream) {
    const float* x     = (const float*)d_in[0];
    const int*   ei    = (const int*)d_in[1];   // [2, E]: src = ei[e], dst = ei[E+e]
    const int*   mask  = (const int*)d_in[2];
    const int*   batch = (const int*)d_in[3];
    const float* Ws    = (const float*)d_in[4]; // [3, 64, 64]
    const float* bs    = (const float*)d_in[5]; // [3, 64]
    const float* lw    = (const float*)d_in[6]; // [64]
    const float* lb    = (const float*)d_in[7]; // [1]
    float* out = (float*)d_out;

    float* ws    = (float*)d_ws;
    float* A     = ws;                               // N*64
    float* B     = A + (size_t)N_NODES * HID;        // N*64
    float* dis   = B + (size_t)N_NODES * HID;        // N
    float* num   = dis + N_NODES;                    // G*64
    float* den   = num + (size_t)N_GRAPHS * HID;     // G
    int*   cnt   = (int*)(den + N_GRAPHS);           // N
    int*   off   = cnt + N_NODES;                    // N+1
    int*   cur   = off + N_NODES + 1;                // N
    int*   bsum  = cur + N_NODES;                    // NB_SCAN
    int*   bpre  = bsum + NB_SCAN;                   // NB_SCAN
    int*   psrc  = bpre + NB_SCAN;                   // E

    hipMemsetAsync(num, 0, ((size_t)N_GRAPHS * HID + N_GRAPHS) * sizeof(float), stream);
    hipMemsetAsync(cnt, 0, (size_t)N_NODES * sizeof(int), stream);

    // ---- CSR build ----
    k_count<<<(N_EDGES + 255) / 256, 256, 0, stream>>>(ei, cnt, N_EDGES);
    k_scan1<<<NB_SCAN, 256, 0, stream>>>(cnt, bsum, N_NODES);
    k_scan2<<<1, 512, 0, stream>>>(bsum, bpre, NB_SCAN);
    k_scan3<<<NB_SCAN, 256, 0, stream>>>(cnt, bpre, off, cur, dis, N_NODES);
    k_fill<<<(N_EDGES + 255) / 256, 256, 0, stream>>>(ei, cur, psrc, N_EDGES);

    // ---- layers ----
    const int row_blocks = (N_NODES + 3) / 4;   // 4 waves/block, 1 row/wave
    for (int l = 0; l < N_LAYERS; l++) {
        const float* in      = (l == 0) ? x : A;
        const float* bias_in = (l == 0) ? bs : bs + (l - 1) * HID;
        k_gemm<<<row_blocks, 256, 0, stream>>>(in, Ws + (size_t)l * HID * HID,
                                               bias_in, (l == 0) ? 0 : 1, dis, B, N_NODES);
        k_agg<<<row_blocks, 256, 0, stream>>>(off, psrc, dis, B, A, N_NODES);
    }

    k_pool<<<(N_NODES + 3) / 4, 256, 0, stream>>>(A, bs + 2 * HID, mask, batch,
                                                  num, den, N_NODES);
    k_final<<<(N_GRAPHS + 3) / 4, 256, 0, stream>>>(num, den, lw, lb, out, N_GRAPHS);
}

// Round 4
// 576.365 us; speedup vs baseline: 2.5218x; 1.1969x over previous
//
#include <hip/hip_runtime.h>
#include <math.h>

#define N_NODES 100000
#define N_EDGES 1600000
#define HID 64
#define N_LAYERS 3
#define N_GRAPHS 500

#define BUK_SHIFT 9
#define BUK_NODES 512                                   // 1 << BUK_SHIFT
#define NBUK ((N_NODES + BUK_NODES - 1) / BUK_NODES)    // 196
#define BIN_BLOCKS 256
#define CHUNK ((N_EDGES + BIN_BLOCKS - 1) / BIN_BLOCKS) // 6250

__device__ __forceinline__ float elu_f(float x) { return x > 0.f ? x : expm1f(x); }

// ---- CSR build v2: bucket sort, no per-edge global atomics ----

// per-block LDS histogram over dst-buckets -> ~50k aggregated global atomics
__global__ void kA_count(const int* __restrict__ ei, int* __restrict__ bcnt) {
    __shared__ int h[NBUK];
    for (int i = threadIdx.x; i < NBUK; i += 256) h[i] = 0;
    __syncthreads();
    int lo = blockIdx.x * CHUNK;
    int hi = min(lo + CHUNK, N_EDGES);
    for (int e = lo + (int)threadIdx.x; e < hi; e += 256)
        atomicAdd(&h[ei[N_EDGES + e] >> BUK_SHIFT], 1);
    __syncthreads();
    for (int i = threadIdx.x; i < NBUK; i += 256)
        if (h[i]) atomicAdd(&bcnt[i], h[i]);
}

// exclusive scan of bucket counts (NBUK=196 <= 256), init cursors
__global__ void kA_scan(const int* __restrict__ bcnt, int* __restrict__ bbase,
                        int* __restrict__ bcur, int* __restrict__ off) {
    __shared__ int s[256];
    int t = threadIdx.x;
    int v = (t < NBUK) ? bcnt[t] : 0;
    s[t] = v;
    __syncthreads();
    for (int o = 1; o < 256; o <<= 1) {
        int u = (t >= o) ? s[t - o] : 0;
        __syncthreads();
        s[t] += u;
        __syncthreads();
    }
    if (t < NBUK) { bbase[t] = s[t] - v; bcur[t] = s[t] - v; }
    if (t == 0) { bbase[NBUK] = N_EDGES; off[N_NODES] = N_EDGES; }
}

// bin edges by dst-bucket; pack src (17b) | dst_local (9b) into 4 bytes
__global__ void kA_bin(const int* __restrict__ ei, int* __restrict__ bcur,
                       unsigned int* __restrict__ bin) {
    __shared__ int h[NBUK];
    __shared__ int rsv[NBUK];
    for (int i = threadIdx.x; i < NBUK; i += 256) h[i] = 0;
    __syncthreads();
    int lo = blockIdx.x * CHUNK;
    int hi = min(lo + CHUNK, N_EDGES);
    for (int e = lo + (int)threadIdx.x; e < hi; e += 256)
        atomicAdd(&h[ei[N_EDGES + e] >> BUK_SHIFT], 1);
    __syncthreads();
    for (int i = threadIdx.x; i < NBUK; i += 256) {
        int c = h[i];
        rsv[i] = c ? atomicAdd(&bcur[i], c) : 0;
        h[i] = 0;   // reuse as local cursor
    }
    __syncthreads();
    for (int e = lo + (int)threadIdx.x; e < hi; e += 256) {
        int d = ei[N_EDGES + e];
        int s = ei[e];
        int b = d >> BUK_SHIFT;
        int pos = rsv[b] + atomicAdd(&h[b], 1);
        bin[pos] = (unsigned)s | ((unsigned)(d & (BUK_NODES - 1)) << 17);
    }
}

// one block per bucket: LDS count + scan -> off/dis/psrc (node-grouped)
__global__ void kB_build(const unsigned int* __restrict__ bin,
                         const int* __restrict__ bbase,
                         int* __restrict__ off, float* __restrict__ dis,
                         int* __restrict__ psrc) {
    __shared__ int cnt[BUK_NODES];
    __shared__ int excl[BUK_NODES];
    __shared__ int ps[256];
    int b = blockIdx.x;
    int t = threadIdx.x;
    int e0 = bbase[b], e1 = bbase[b + 1];
    cnt[t] = 0; cnt[t + 256] = 0;
    __syncthreads();
    for (int e = e0 + t; e < e1; e += 256)
        atomicAdd(&cnt[bin[e] >> 17], 1);
    __syncthreads();
    int psum = cnt[2 * t] + cnt[2 * t + 1];
    ps[t] = psum;
    __syncthreads();
    for (int o = 1; o < 256; o <<= 1) {
        int u = (t >= o) ? ps[t - o] : 0;
        __syncthreads();
        ps[t] += u;
        __syncthreads();
    }
    int pexcl = ps[t] - psum;
    excl[2 * t] = pexcl;
    excl[2 * t + 1] = pexcl + cnt[2 * t];
    __syncthreads();
    int n0 = b << BUK_SHIFT;
    for (int i = t; i < BUK_NODES; i += 256) {
        int n = n0 + i;
        if (n < N_NODES) {
            off[n] = e0 + excl[i];
            dis[n] = rsqrtf((float)cnt[i] + 1.0f);   // +1 self loop
        }
    }
    __syncthreads();
    cnt[t] = excl[t]; cnt[t + 256] = excl[t + 256];  // cnt becomes cursor
    __syncthreads();
    for (int e = e0 + t; e < e1; e += 256) {
        unsigned v = bin[e];
        int dloc = v >> 17;
        int pos = e0 + atomicAdd(&cnt[dloc], 1);
        psrc[pos] = (int)(v & 0x1FFFFu);
    }
}

// ---- per-layer kernels ----

// One wave per row. B = (act(X) @ W) * dis[row]
__global__ void k_gemm(const float* __restrict__ X, const float* __restrict__ W,
                       const float* __restrict__ bias, int act,
                       const float* __restrict__ dis, float* __restrict__ B, int n) {
    int lane = threadIdx.x & 63;
    int wid = (blockIdx.x * blockDim.x + threadIdx.x) >> 6;
    if (wid >= n) return;
    float xv = X[(size_t)wid * HID + lane];
    if (act) xv = elu_f(xv + bias[lane]);
    float acc = 0.f;
#pragma unroll
    for (int k = 0; k < HID; k++)
        acc = fmaf(__shfl(xv, k), W[k * HID + lane], acc);
    B[(size_t)wid * HID + lane] = acc * dis[wid];
}

// One wave per dst node: A[dst] = dis[dst] * (B[dst] + sum_{in} B[src])
__global__ void k_agg(const int* __restrict__ off, const int* __restrict__ psrc,
                      const float* __restrict__ dis, const float* __restrict__ B,
                      float* __restrict__ A, int n) {
    int lane = threadIdx.x & 63;
    int node = __builtin_amdgcn_readfirstlane((blockIdx.x * blockDim.x + threadIdx.x) >> 6);
    if (node >= n) return;
    float acc = B[(size_t)node * HID + lane];
    int p0 = off[node], p1 = off[node + 1];
    int p = p0;
    for (; p + 8 <= p1; p += 8) {
        int s0 = psrc[p+0], s1 = psrc[p+1], s2 = psrc[p+2], s3 = psrc[p+3];
        int s4 = psrc[p+4], s5 = psrc[p+5], s6 = psrc[p+6], s7 = psrc[p+7];
        float b0 = B[(size_t)s0*HID+lane], b1 = B[(size_t)s1*HID+lane];
        float b2 = B[(size_t)s2*HID+lane], b3 = B[(size_t)s3*HID+lane];
        float b4 = B[(size_t)s4*HID+lane], b5 = B[(size_t)s5*HID+lane];
        float b6 = B[(size_t)s6*HID+lane], b7 = B[(size_t)s7*HID+lane];
        acc += ((b0 + b1) + (b2 + b3)) + ((b4 + b5) + (b6 + b7));
    }
    if (p + 4 <= p1) {
        int s0 = psrc[p+0], s1 = psrc[p+1], s2 = psrc[p+2], s3 = psrc[p+3];
        float b0 = B[(size_t)s0*HID+lane], b1 = B[(size_t)s1*HID+lane];
        float b2 = B[(size_t)s2*HID+lane], b3 = B[(size_t)s3*HID+lane];
        acc += (b0 + b1) + (b2 + b3);
        p += 4;
    }
    if (p + 2 <= p1) {
        int s0 = psrc[p+0], s1 = psrc[p+1];
        acc += B[(size_t)s0*HID+lane] + B[(size_t)s1*HID+lane];
        p += 2;
    }
    if (p < p1) acc += B[(size_t)psrc[p]*HID+lane];
    A[(size_t)node * HID + lane] = acc * dis[node];
}

__global__ void k_pool(const float* __restrict__ A, const float* __restrict__ bias,
                       const int* __restrict__ mask, const int* __restrict__ batch,
                       float* __restrict__ num, float* __restrict__ den, int n) {
    int lane = threadIdx.x & 63;
    int wid = (blockIdx.x * blockDim.x + threadIdx.x) >> 6;
    if (wid >= n) return;
    if (!mask[wid]) return;
    int g = batch[wid];
    float h = elu_f(A[(size_t)wid * HID + lane] + bias[lane]);
    atomicAdd(&num[g * HID + lane], h);
    if (lane == 0) atomicAdd(&den[g], 1.0f);
}

__global__ void k_final(const float* __restrict__ num, const float* __restrict__ den,
                        const float* __restrict__ w, const float* __restrict__ b,
                        float* __restrict__ out, int G) {
    int lane = threadIdx.x & 63;
    int g = (blockIdx.x * blockDim.x + threadIdx.x) >> 6;
    if (g >= G) return;
    float v = num[g * HID + lane] / fmaxf(den[g], 1.0f) * w[lane];
#pragma unroll
    for (int off = 32; off > 0; off >>= 1) v += __shfl_down(v, off);
    if (lane == 0) out[g] = v + b[0];
}

extern "C" void kernel_launch(void* const* d_in, const int* in_sizes, int n_in,
                              void* d_out, int out_size, void* d_ws, size_t ws_size,
                              hipStream_t stream) {
    const float* x     = (const float*)d_in[0];
    const int*   ei    = (const int*)d_in[1];   // [2, E]: src = ei[e], dst = ei[E+e]
    const int*   mask  = (const int*)d_in[2];
    const int*   batch = (const int*)d_in[3];
    const float* Ws    = (const float*)d_in[4]; // [3, 64, 64]
    const float* bs    = (const float*)d_in[5]; // [3, 64]
    const float* lw    = (const float*)d_in[6]; // [64]
    const float* lb    = (const float*)d_in[7]; // [1]
    float* out = (float*)d_out;

    float* ws    = (float*)d_ws;
    float* A     = ws;                               // N*64
    float* B     = A + (size_t)N_NODES * HID;        // N*64 (bin aliases this)
    float* dis   = B + (size_t)N_NODES * HID;        // N
    float* num   = dis + N_NODES;                    // G*64
    float* den   = num + (size_t)N_GRAPHS * HID;     // G
    int*   off   = (int*)(den + N_GRAPHS);           // N+1
    int*   psrc  = off + N_NODES + 1;                // E
    int*   bcnt  = psrc + N_EDGES;                   // NBUK
    int*   bbase = bcnt + NBUK;                      // NBUK+1
    int*   bcur  = bbase + NBUK + 1;                 // NBUK
    unsigned int* bin = (unsigned int*)B;            // E (dead before first gemm)

    hipMemsetAsync(num, 0, ((size_t)N_GRAPHS * HID + N_GRAPHS) * sizeof(float), stream);
    hipMemsetAsync(bcnt, 0, NBUK * sizeof(int), stream);

    // ---- CSR build (bucket sort) ----
    kA_count<<<BIN_BLOCKS, 256, 0, stream>>>(ei, bcnt);
    kA_scan<<<1, 256, 0, stream>>>(bcnt, bbase, bcur, off);
    kA_bin<<<BIN_BLOCKS, 256, 0, stream>>>(ei, bcur, bin);
    kB_build<<<NBUK, 256, 0, stream>>>(bin, bbase, off, dis, psrc);

    // ---- layers ----
    const int row_blocks = (N_NODES + 3) / 4;   // 4 waves/block, 1 row/wave
    for (int l = 0; l < N_LAYERS; l++) {
        const float* in      = (l == 0) ? x : A;
        const float* bias_in = (l == 0) ? bs : bs + (l - 1) * HID;
        k_gemm<<<row_blocks, 256, 0, stream>>>(in, Ws + (size_t)l * HID * HID,
                                               bias_in, (l == 0) ? 0 : 1, dis, B, N_NODES);
        k_agg<<<row_blocks, 256, 0, stream>>>(off, psrc, dis, B, A, N_NODES);
    }

    k_pool<<<(N_NODES + 3) / 4, 256, 0, stream>>>(A, bs + 2 * HID, mask, batch,
                                                  num, den, N_NODES);
    k_final<<<(N_GRAPHS + 3) / 4, 256, 0, stream>>>(num, den, lw, lb, out, N_GRAPHS);
}

// Round 5
// 474.026 us; speedup vs baseline: 3.0662x; 1.2159x over previous
//
#include <hip/hip_runtime.h>
#include <math.h>

#define N_NODES 100000
#define N_EDGES 1600000
#define HID 64
#define N_LAYERS 3
#define N_GRAPHS 500

#define BUK_SHIFT 9
#define BUK_NODES 512                                   // 1 << BUK_SHIFT
#define NBUK ((N_NODES + BUK_NODES - 1) / BUK_NODES)    // 196
#define BIN_BLOCKS 256
#define CHUNK ((N_EDGES + BIN_BLOCKS - 1) / BIN_BLOCKS) // 6250

__device__ __forceinline__ float elu_f(float x) { return x > 0.f ? x : expm1f(x); }

// ---- CSR build: bucket sort, no per-edge global atomics ----

__global__ void kA_count(const int* __restrict__ ei, int* __restrict__ bcnt) {
    __shared__ int h[NBUK];
    for (int i = threadIdx.x; i < NBUK; i += 256) h[i] = 0;
    __syncthreads();
    int lo = blockIdx.x * CHUNK;
    int hi = min(lo + CHUNK, N_EDGES);
    for (int e = lo + (int)threadIdx.x; e < hi; e += 256)
        atomicAdd(&h[ei[N_EDGES + e] >> BUK_SHIFT], 1);
    __syncthreads();
    for (int i = threadIdx.x; i < NBUK; i += 256)
        if (h[i]) atomicAdd(&bcnt[i], h[i]);
}

__global__ void kA_scan(const int* __restrict__ bcnt, int* __restrict__ bbase,
                        int* __restrict__ bcur, int* __restrict__ off) {
    __shared__ int s[256];
    int t = threadIdx.x;
    int v = (t < NBUK) ? bcnt[t] : 0;
    s[t] = v;
    __syncthreads();
    for (int o = 1; o < 256; o <<= 1) {
        int u = (t >= o) ? s[t - o] : 0;
        __syncthreads();
        s[t] += u;
        __syncthreads();
    }
    if (t < NBUK) { bbase[t] = s[t] - v; bcur[t] = s[t] - v; }
    if (t == 0) { bbase[NBUK] = N_EDGES; off[N_NODES] = N_EDGES; }
}

__global__ void kA_bin(const int* __restrict__ ei, int* __restrict__ bcur,
                       unsigned int* __restrict__ bin) {
    __shared__ int h[NBUK];
    __shared__ int rsv[NBUK];
    for (int i = threadIdx.x; i < NBUK; i += 256) h[i] = 0;
    __syncthreads();
    int lo = blockIdx.x * CHUNK;
    int hi = min(lo + CHUNK, N_EDGES);
    for (int e = lo + (int)threadIdx.x; e < hi; e += 256)
        atomicAdd(&h[ei[N_EDGES + e] >> BUK_SHIFT], 1);
    __syncthreads();
    for (int i = threadIdx.x; i < NBUK; i += 256) {
        int c = h[i];
        rsv[i] = c ? atomicAdd(&bcur[i], c) : 0;
        h[i] = 0;   // reuse as local cursor
    }
    __syncthreads();
    for (int e = lo + (int)threadIdx.x; e < hi; e += 256) {
        int d = ei[N_EDGES + e];
        int s = ei[e];
        int b = d >> BUK_SHIFT;
        int pos = rsv[b] + atomicAdd(&h[b], 1);
        bin[pos] = (unsigned)s | ((unsigned)(d & (BUK_NODES - 1)) << 17);
    }
}

__global__ void kB_build(const unsigned int* __restrict__ bin,
                         const int* __restrict__ bbase,
                         int* __restrict__ off, float* __restrict__ dis,
                         int* __restrict__ psrc) {
    __shared__ int cnt[BUK_NODES];
    __shared__ int excl[BUK_NODES];
    __shared__ int ps[256];
    int b = blockIdx.x;
    int t = threadIdx.x;
    int e0 = bbase[b], e1 = bbase[b + 1];
    cnt[t] = 0; cnt[t + 256] = 0;
    __syncthreads();
    for (int e = e0 + t; e < e1; e += 256)
        atomicAdd(&cnt[bin[e] >> 17], 1);
    __syncthreads();
    int psum = cnt[2 * t] + cnt[2 * t + 1];
    ps[t] = psum;
    __syncthreads();
    for (int o = 1; o < 256; o <<= 1) {
        int u = (t >= o) ? ps[t - o] : 0;
        __syncthreads();
        ps[t] += u;
        __syncthreads();
    }
    int pexcl = ps[t] - psum;
    excl[2 * t] = pexcl;
    excl[2 * t + 1] = pexcl + cnt[2 * t];
    __syncthreads();
    int n0 = b << BUK_SHIFT;
    for (int i = t; i < BUK_NODES; i += 256) {
        int n = n0 + i;
        if (n < N_NODES) {
            off[n] = e0 + excl[i];
            dis[n] = rsqrtf((float)cnt[i] + 1.0f);   // +1 self loop
        }
    }
    __syncthreads();
    cnt[t] = excl[t]; cnt[t + 256] = excl[t + 256];  // cnt becomes cursor
    __syncthreads();
    for (int e = e0 + t; e < e1; e += 256) {
        unsigned v = bin[e];
        int dloc = v >> 17;
        int pos = e0 + atomicAdd(&cnt[dloc], 1);
        psrc[pos] = (int)(v & 0x1FFFFu);
    }
}

// ---- per-layer kernels ----

// One wave per row. B = (act(X) @ W) * dis[row]
__global__ void k_gemm(const float* __restrict__ X, const float* __restrict__ W,
                       const float* __restrict__ bias, int act,
                       const float* __restrict__ dis, float* __restrict__ B, int n) {
    int lane = threadIdx.x & 63;
    int wid = (blockIdx.x * blockDim.x + threadIdx.x) >> 6;
    if (wid >= n) return;
    float xv = X[(size_t)wid * HID + lane];
    if (act) xv = elu_f(xv + bias[lane]);
    float acc = 0.f;
#pragma unroll
    for (int k = 0; k < HID; k++)
        acc = fmaf(__shfl(xv, k), W[k * HID + lane], acc);
    B[(size_t)wid * HID + lane] = acc * dis[wid];
}

// One wave per dst node: A[dst] = dis[dst] * (B[dst] + sum_{in} B[src])
__global__ void k_agg(const int* __restrict__ off, const int* __restrict__ psrc,
                      const float* __restrict__ dis, const float* __restrict__ B,
                      float* __restrict__ A, int n) {
    int lane = threadIdx.x & 63;
    int node = __builtin_amdgcn_readfirstlane((blockIdx.x * blockDim.x + threadIdx.x) >> 6);
    if (node >= n) return;
    float acc = B[(size_t)node * HID + lane];
    int p0 = off[node], p1 = off[node + 1];
    int p = p0;
    for (; p + 8 <= p1; p += 8) {
        int s0 = psrc[p+0], s1 = psrc[p+1], s2 = psrc[p+2], s3 = psrc[p+3];
        int s4 = psrc[p+4], s5 = psrc[p+5], s6 = psrc[p+6], s7 = psrc[p+7];
        float b0 = B[(size_t)s0*HID+lane], b1 = B[(size_t)s1*HID+lane];
        float b2 = B[(size_t)s2*HID+lane], b3 = B[(size_t)s3*HID+lane];
        float b4 = B[(size_t)s4*HID+lane], b5 = B[(size_t)s5*HID+lane];
        float b6 = B[(size_t)s6*HID+lane], b7 = B[(size_t)s7*HID+lane];
        acc += ((b0 + b1) + (b2 + b3)) + ((b4 + b5) + (b6 + b7));
    }
    if (p + 4 <= p1) {
        int s0 = psrc[p+0], s1 = psrc[p+1], s2 = psrc[p+2], s3 = psrc[p+3];
        float b0 = B[(size_t)s0*HID+lane], b1 = B[(size_t)s1*HID+lane];
        float b2 = B[(size_t)s2*HID+lane], b3 = B[(size_t)s3*HID+lane];
        acc += (b0 + b1) + (b2 + b3);
        p += 4;
    }
    if (p + 2 <= p1) {
        int s0 = psrc[p+0], s1 = psrc[p+1];
        acc += B[(size_t)s0*HID+lane] + B[(size_t)s1*HID+lane];
        p += 2;
    }
    if (p < p1) acc += B[(size_t)psrc[p]*HID+lane];
    A[(size_t)node * HID + lane] = acc * dis[node];
}

// One block per graph (batch is sorted): binary-search node range, register
// accumulate masked elu(A+bias), LDS cross-wave reduce, dot w, write out[g].
__global__ void k_pool_final(const float* __restrict__ A, const float* __restrict__ bias,
                             const int* __restrict__ mask, const int* __restrict__ batch,
                             const float* __restrict__ w, const float* __restrict__ b,
                             float* __restrict__ out) {
    __shared__ float sacc[4][HID];
    __shared__ float scnt[4];
    int g = blockIdx.x;
    int t = threadIdx.x;
    int lane = t & 63;
    int wv = t >> 6;

    // lower_bound(batch, g) and lower_bound(batch, g+1)
    int lo = 0, hi = N_NODES;
    while (lo < hi) { int mid = (lo + hi) >> 1; if (batch[mid] < g) lo = mid + 1; else hi = mid; }
    int n0 = lo;
    hi = N_NODES;
    while (lo < hi) { int mid = (lo + hi) >> 1; if (batch[mid] < g + 1) lo = mid + 1; else hi = mid; }
    int n1 = lo;

    float bl = bias[lane];
    float acc0 = 0.f, acc1 = 0.f;
    float cnt0 = 0.f, cnt1 = 0.f;
    int n = n0 + wv;
    for (; n + 4 < n1; n += 8) {         // 2 nodes in flight per wave
        int m0 = mask[n], m1 = mask[n + 4];
        float v0 = A[(size_t)n * HID + lane];
        float v1 = A[(size_t)(n + 4) * HID + lane];
        if (m0) { acc0 += elu_f(v0 + bl); cnt0 += 1.f; }
        if (m1) { acc1 += elu_f(v1 + bl); cnt1 += 1.f; }
    }
    if (n < n1 && mask[n]) { acc0 += elu_f(A[(size_t)n * HID + lane] + bl); cnt0 += 1.f; }
    acc0 += acc1; cnt0 += cnt1;

    sacc[wv][lane] = acc0;
    if (lane == 0) scnt[wv] = cnt0;
    __syncthreads();
    if (wv == 0) {
        float v = sacc[0][lane] + sacc[1][lane] + sacc[2][lane] + sacc[3][lane];
        float c = scnt[0] + scnt[1] + scnt[2] + scnt[3];
        v = v / fmaxf(c, 1.0f) * w[lane];
#pragma unroll
        for (int o = 32; o > 0; o >>= 1) v += __shfl_down(v, o);
        if (lane == 0) out[g] = v + b[0];
    }
}

extern "C" void kernel_launch(void* const* d_in, const int* in_sizes, int n_in,
                              void* d_out, int out_size, void* d_ws, size_t ws_size,
                              hipStream_t stream) {
    const float* x     = (const float*)d_in[0];
    const int*   ei    = (const int*)d_in[1];   // [2, E]: src = ei[e], dst = ei[E+e]
    const int*   mask  = (const int*)d_in[2];
    const int*   batch = (const int*)d_in[3];
    const float* Ws    = (const float*)d_in[4]; // [3, 64, 64]
    const float* bs    = (const float*)d_in[5]; // [3, 64]
    const float* lw    = (const float*)d_in[6]; // [64]
    const float* lb    = (const float*)d_in[7]; // [1]
    float* out = (float*)d_out;

    float* ws    = (float*)d_ws;
    float* A     = ws;                               // N*64
    float* B     = A + (size_t)N_NODES * HID;        // N*64 (bin aliases this)
    float* dis   = B + (size_t)N_NODES * HID;        // N
    int*   off   = (int*)(dis + N_NODES);            // N+1
    int*   psrc  = off + N_NODES + 1;                // E
    int*   bcnt  = psrc + N_EDGES;                   // NBUK
    int*   bbase = bcnt + NBUK;                      // NBUK+1
    int*   bcur  = bbase + NBUK + 1;                 // NBUK
    unsigned int* bin = (unsigned int*)B;            // E (dead before first gemm)

    hipMemsetAsync(bcnt, 0, NBUK * sizeof(int), stream);

    // ---- CSR build (bucket sort) ----
    kA_count<<<BIN_BLOCKS, 256, 0, stream>>>(ei, bcnt);
    kA_scan<<<1, 256, 0, stream>>>(bcnt, bbase, bcur, off);
    kA_bin<<<BIN_BLOCKS, 256, 0, stream>>>(ei, bcur, bin);
    kB_build<<<NBUK, 256, 0, stream>>>(bin, bbase, off, dis, psrc);

    // ---- layers ----
    const int row_blocks = (N_NODES + 3) / 4;   // 4 waves/block, 1 row/wave
    for (int l = 0; l < N_LAYERS; l++) {
        const float* in      = (l == 0) ? x : A;
        const float* bias_in = (l == 0) ? bs : bs + (l - 1) * HID;
        k_gemm<<<row_blocks, 256, 0, stream>>>(in, Ws + (size_t)l * HID * HID,
                                               bias_in, (l == 0) ? 0 : 1, dis, B, N_NODES);
        k_agg<<<row_blocks, 256, 0, stream>>>(off, psrc, dis, B, A, N_NODES);
    }

    k_pool_final<<<N_GRAPHS, 256, 0, stream>>>(A, bs + 2 * HID, mask, batch, lw, lb, out);
}